// Round 3
// baseline (322.952 us; speedup 1.0000x reference)
//
#include <hip/hip_runtime.h>
#include <hip/hip_bf16.h>

// DiscoMixerBlock: B=1, H=90, W=180 (P=16200), MODEL_DIM=130 (L=128),
// NH=8, HD=16, S=16, K=25, NNB=25, MH=32, FH=256. All fp32.
#define P_TOT 16200
#define MODEL_DIMC 130
#define L_DIM 128
#define NHH 8
#define S_DIM 16
#define K_DIM 25
#define NNBC 25
#define MH_DIM 32
#define FH_DIM 256

// exact gelu: x * 0.5 * (1 + erf(x/sqrt(2))); erf via Abramowitz-Stegun 7.1.26 (|err|<=1.5e-7)
__device__ __forceinline__ float gelu_f(float x) {
    float z = fabsf(x) * 0.70710678118654752440f;
    float t = __builtin_amdgcn_rcpf(fmaf(0.3275911f, z, 1.0f));
    float poly = t * fmaf(t, fmaf(t, fmaf(t, fmaf(t, 1.061405429f, -1.453152027f),
                                          1.421413741f), -0.284496736f), 0.254829592f);
    float e = __expf(-z * z);
    float erfp = fmaf(-poly, e, 1.0f);     // erf(|x|/sqrt2), >=0
    float erfv = copysignf(erfp, x);
    return 0.5f * x * (1.0f + erfv);
}

// ---------------- K0: transpose head_w1 [h][s][m] -> w1t [h][m][s] (4096 elems) ----------------
__global__ __launch_bounds__(256) void k0_transpose_w1(const float* __restrict__ hw1,
                                                       float* __restrict__ w1t) {
    int i = blockIdx.x * 256 + threadIdx.x;
    if (i < NHH * S_DIM * MH_DIM) {
        int h = i >> 9, s = (i >> 5) & 15, m = i & 31;
        w1t[h * 512 + m * 16 + s] = hw1[i];
    }
}

// ---------------- K1: bw[p][n][s] = sum_k disco_w[s][k] * basis[k][p][n] ----------------
__global__ __launch_bounds__(256) void k1_bw(const float* __restrict__ basis,
                                             const float* __restrict__ disco_w,
                                             float* __restrict__ bw) {
    __shared__ float w[S_DIM * K_DIM];   // [s][k]
    int tid = threadIdx.x;
    for (int i = tid; i < S_DIM * K_DIM; i += 256) w[i] = disco_w[i];
    __syncthreads();
    int i = blockIdx.x * 256 + tid;      // flat (p,n)
    if (i >= P_TOT * NNBC) return;
    float bv[K_DIM];
#pragma unroll
    for (int k = 0; k < K_DIM; k++) bv[k] = basis[k * (P_TOT * NNBC) + i];
    float acc[S_DIM];
#pragma unroll
    for (int s = 0; s < S_DIM; s++) {
        float a = 0.f;
#pragma unroll
        for (int k = 0; k < K_DIM; k++) a = fmaf(w[s * K_DIM + k], bv[k], a);
        acc[s] = a;
    }
    float4* outp = (float4*)(bw + (size_t)i * S_DIM);
#pragma unroll
    for (int q = 0; q < 4; q++) {
        float4 v; v.x = acc[q*4+0]; v.y = acc[q*4+1]; v.z = acc[q*4+2]; v.w = acc[q*4+3];
        outp[q] = v;
    }
}

// ---------------- K2: fused disco gather-dot + head MLP + residual -> xmix[p][c] ----------------
// Block = 4 waves = 4 points. Phase 1: wave = point, lane owns channels {lane, lane+64};
// bw/nbr via wave-uniform s_load -> SGPR (zero LDS in hot loop).
// Phase 3: wave = head (x2 sequential), lanes = 4 pts x 16 d; w1t rows via s_load.
#define YSTR 2056   // per-point LDS stride (16*128 + 8): pads banks across pts
__global__ __launch_bounds__(256, 4) void k2_disco_head(
        const float* __restrict__ x, const int* __restrict__ nbr,
        const float* __restrict__ bw, const float* __restrict__ w1t,
        const float* __restrict__ head_b1, const float* __restrict__ head_w2,
        const float* __restrict__ head_b2, const float* __restrict__ disco_b,
        float* __restrict__ xmix) {
    __shared__ float ylds[4 * YSTR];     // [pt][s][c]: pt*YSTR + s*128 + c

    int tid  = threadIdx.x;
    int lane = tid & 63;
    int wv   = __builtin_amdgcn_readfirstlane(tid >> 6);   // uniform wave id 0..3
    int p0   = blockIdx.x * 4;
    int p    = p0 + wv;                                    // uniform point

    const float* bwp = bw + (size_t)p * (NNBC * S_DIM);    // uniform base
    const int*   nbp = nbr + p * NNBC;                     // uniform base

    float y0[16], y1[16];
#pragma unroll
    for (int s = 0; s < 16; s++) { float db = disco_b[s]; y0[s] = db; y1[s] = db; }

    const float* xb0 = x + lane;
    const float* xb1 = x + 64 + lane;

    // 6 chunks of 4 neighbors (uniform s_load: 4 idx + 64 bw per chunk), then tail n=24
#pragma unroll 1
    for (int nb = 0; nb < 24; nb += 4) {
#pragma unroll
        for (int j = 0; j < 4; j++) {
            int u = nbp[nb + j];                           // uniform -> SGPR
            float g0 = xb0[(size_t)u * MODEL_DIMC];
            float g1 = xb1[(size_t)u * MODEL_DIMC];
#pragma unroll
            for (int s = 0; s < 16; s++) {
                float wv_ = bwp[(nb + j) * 16 + s];        // uniform -> SGPR
                y0[s] = fmaf(g0, wv_, y0[s]);
                y1[s] = fmaf(g1, wv_, y1[s]);
            }
        }
    }
    {
        int u = nbp[24];
        float g0 = xb0[(size_t)u * MODEL_DIMC];
        float g1 = xb1[(size_t)u * MODEL_DIMC];
#pragma unroll
        for (int s = 0; s < 16; s++) {
            float wv_ = bwp[24 * 16 + s];
            y0[s] = fmaf(g0, wv_, y0[s]);
            y1[s] = fmaf(g1, wv_, y1[s]);
        }
    }

    // Phase 2: y -> LDS. write2-friendly pairs (c, c+64); lanes consecutive -> conflict-free
#pragma unroll
    for (int s = 0; s < 16; s++) {
        ylds[wv * YSTR + s * 128 + lane]      = y0[s];
        ylds[wv * YSTR + s * 128 + 64 + lane] = y1[s];
    }
    __syncthreads();

    // Phase 3: wave handles heads {wv, wv+4}; lane -> (ptl = lane>>4, d = lane&15)
    int ptl = lane >> 4;
    int d   = lane & 15;
#pragma unroll
    for (int t = 0; t < 2; t++) {
        int hh = __builtin_amdgcn_readfirstlane(wv + 4 * t);
        float yv[16];
#pragma unroll
        for (int s = 0; s < 16; s++)
            yv[s] = ylds[ptl * YSTR + s * 128 + hh * 16 + d];   // <=2 lanes/bank
        const float* wrow = w1t + hh * (MH_DIM * S_DIM);        // uniform
        const float* b1r  = head_b1 + hh * MH_DIM;
        const float* w2r  = head_w2 + hh * MH_DIM;
        float acc = head_b2[hh];
#pragma unroll 2
        for (int m = 0; m < MH_DIM; m++) {
            float a = b1r[m];                                   // uniform -> SGPR
#pragma unroll
            for (int s = 0; s < 16; s++)
                a = fmaf(yv[s], wrow[m * 16 + s], a);           // w uniform -> SGPR
            a = gelu_f(a);
            acc = fmaf(a, w2r[m], acc);
        }
        int pp = p0 + ptl;
        int c  = hh * 16 + d;
        xmix[pp * L_DIM + c] = acc + x[(size_t)pp * MODEL_DIMC + c];
    }
}

// ---------------- K3a: hf[p][f] = gelu(xmix[p][:] @ w1[:128][f] + b1[f]) ----------------
// block 256 = 32 pts x 256 f; lane: fg=tid&15 -> 16 f, pg=tid>>4 -> 2 pts
__global__ __launch_bounds__(256, 4) void k3a_ffn1(
        const float* __restrict__ xmix, const float* __restrict__ w1,
        const float* __restrict__ b1, float* __restrict__ hf) {
    __shared__ __align__(16) float xm[32 * 132];    // padded stride 132
    int tid = threadIdx.x;
    int p0 = blockIdx.x * 32;
    int valid = min(32, P_TOT - p0);
    {
        const float4* src = (const float4*)(xmix + (size_t)p0 * L_DIM);
        for (int j = tid; j < valid * 32; j += 256) {
            float4 v = src[j];
            int pt = j >> 5, q = j & 31;
            *(float4*)&xm[pt * 132 + q * 4] = v;
        }
    }
    __syncthreads();

    int fg = tid & 15, pg = tid >> 4;
    int f0 = fg * 16;
    float acc[2][16];
#pragma unroll
    for (int j = 0; j < 16; j++) { float bb = b1[f0 + j]; acc[0][j] = bb; acc[1][j] = bb; }
    const float* xr0 = &xm[(pg * 2 + 0) * 132];
    const float* xr1 = &xm[(pg * 2 + 1) * 132];
#pragma unroll 2
    for (int k = 0; k < 128; k++) {
        float xa = xr0[k], xb = xr1[k];
        const float4* wr = (const float4*)&w1[k * FH_DIM + f0];
#pragma unroll
        for (int q = 0; q < 4; q++) {
            float4 w4 = wr[q];
            acc[0][q*4+0] = fmaf(xa, w4.x, acc[0][q*4+0]);
            acc[0][q*4+1] = fmaf(xa, w4.y, acc[0][q*4+1]);
            acc[0][q*4+2] = fmaf(xa, w4.z, acc[0][q*4+2]);
            acc[0][q*4+3] = fmaf(xa, w4.w, acc[0][q*4+3]);
            acc[1][q*4+0] = fmaf(xb, w4.x, acc[1][q*4+0]);
            acc[1][q*4+1] = fmaf(xb, w4.y, acc[1][q*4+1]);
            acc[1][q*4+2] = fmaf(xb, w4.z, acc[1][q*4+2]);
            acc[1][q*4+3] = fmaf(xb, w4.w, acc[1][q*4+3]);
        }
    }
#pragma unroll
    for (int i = 0; i < 2; i++) {
        int pl = pg * 2 + i;
        if (pl < valid) {
            float4* hp = (float4*)(hf + (size_t)(p0 + pl) * FH_DIM + f0);
#pragma unroll
            for (int q = 0; q < 4; q++) {
                float4 v;
                v.x = gelu_f(acc[i][q*4+0]);
                v.y = gelu_f(acc[i][q*4+1]);
                v.z = gelu_f(acc[i][q*4+2]);
                v.w = gelu_f(acc[i][q*4+3]);
                hp[q] = v;
            }
        }
    }
}

// ---------------- K3b: out[p][l] = hf[p][:] @ w2[:][l] + b2[l] + xmix[p][l]; +sincos ----------------
// block 256 = 32 pts x 128 l; lane: lg=tid&31 -> 4 l, pg=tid>>5 -> 4 pts
__global__ __launch_bounds__(256, 4) void k3b_ffn2(
        const float* __restrict__ x, const float* __restrict__ xmix,
        const float* __restrict__ hf, const float* __restrict__ w2,
        const float* __restrict__ b2, float* __restrict__ out) {
    __shared__ __align__(16) float hfl[32 * 260];   // padded stride 260
    int tid = threadIdx.x;
    int p0 = blockIdx.x * 32;
    int valid = min(32, P_TOT - p0);
    {
        const float4* src = (const float4*)(hf + (size_t)p0 * FH_DIM);
        for (int j = tid; j < valid * 64; j += 256) {
            float4 v = src[j];
            int pt = j >> 6, q = j & 63;
            *(float4*)&hfl[pt * 260 + q * 4] = v;
        }
    }
    __syncthreads();

    int lg = tid & 31, pg = tid >> 5;
    float4 bb = *(const float4*)&b2[lg * 4];
    float acc2[4][4];
#pragma unroll
    for (int i = 0; i < 4; i++) {
        acc2[i][0] = bb.x; acc2[i][1] = bb.y; acc2[i][2] = bb.z; acc2[i][3] = bb.w;
    }
#pragma unroll 2
    for (int f = 0; f < FH_DIM; f++) {
        float4 wv4 = *(const float4*)&w2[f * L_DIM + lg * 4];
#pragma unroll
        for (int i = 0; i < 4; i++) {
            float hv = hfl[(pg * 4 + i) * 260 + f];
            acc2[i][0] = fmaf(hv, wv4.x, acc2[i][0]);
            acc2[i][1] = fmaf(hv, wv4.y, acc2[i][1]);
            acc2[i][2] = fmaf(hv, wv4.z, acc2[i][2]);
            acc2[i][3] = fmaf(hv, wv4.w, acc2[i][3]);
        }
    }
#pragma unroll
    for (int i = 0; i < 4; i++) {
        int pl = pg * 4 + i;
        if (pl < valid) {
            int pp = p0 + pl;
            float4 xm4 = *(const float4*)&xmix[(size_t)pp * L_DIM + lg * 4];
            float2 o01, o23;
            o01.x = acc2[i][0] + xm4.x;
            o01.y = acc2[i][1] + xm4.y;
            o23.x = acc2[i][2] + xm4.z;
            o23.y = acc2[i][3] + xm4.w;
            *(float2*)&out[(size_t)pp * MODEL_DIMC + lg * 4]     = o01;
            *(float2*)&out[(size_t)pp * MODEL_DIMC + lg * 4 + 2] = o23;
        }
    }
    if (tid < 64) {
        int pt = tid >> 1, wch = tid & 1;
        if (pt < valid) {
            int pp = p0 + pt;
            out[(size_t)pp * MODEL_DIMC + 128 + wch] = x[(size_t)pp * MODEL_DIMC + 128 + wch];
        }
    }
}

extern "C" void kernel_launch(void* const* d_in, const int* in_sizes, int n_in,
                              void* d_out, int out_size, void* d_ws, size_t ws_size,
                              hipStream_t stream) {
    const float* x        = (const float*)d_in[0];
    const int*   nbr      = (const int*)  d_in[1];
    const float* basis    = (const float*)d_in[2];
    const float* disco_w  = (const float*)d_in[3];
    const float* disco_b  = (const float*)d_in[4];
    const float* head_w1  = (const float*)d_in[5];
    const float* head_b1  = (const float*)d_in[6];
    const float* head_w2  = (const float*)d_in[7];
    const float* head_b2  = (const float*)d_in[8];
    const float* ffn_w1   = (const float*)d_in[9];
    const float* ffn_b1   = (const float*)d_in[10];
    const float* ffn_w2   = (const float*)d_in[11];
    const float* ffn_b2   = (const float*)d_in[12];
    float* out = (float*)d_out;

    // ws layout: bw [P*400] (25.9MB) | xmix [P*128] (8.3MB) | w1t [4096] (16KB)
    // hf [P*256] aliases bw (bw dead after k2).
    float* bw   = (float*)d_ws;
    float* xmix = bw + (size_t)P_TOT * NNBC * S_DIM;
    float* w1t  = xmix + (size_t)P_TOT * L_DIM;
    float* hf   = bw;

    hipLaunchKernelGGL(k0_transpose_w1, dim3(16), dim3(256), 0, stream, head_w1, w1t);
    hipLaunchKernelGGL(k1_bw, dim3((P_TOT * NNBC + 255) / 256), dim3(256), 0, stream,
                       basis, disco_w, bw);
    hipLaunchKernelGGL(k2_disco_head, dim3(P_TOT / 4), dim3(256), 0, stream,
                       x, nbr, bw, w1t, head_b1, head_w2, head_b2, disco_b, xmix);
    hipLaunchKernelGGL(k3a_ffn1, dim3((P_TOT + 31) / 32), dim3(256), 0, stream,
                       xmix, ffn_w1, ffn_b1, hf);
    hipLaunchKernelGGL(k3b_ffn2, dim3((P_TOT + 31) / 32), dim3(256), 0, stream,
                       x, xmix, hf, ffn_w2, ffn_b2, out);
}

// Round 4
// 272.836 us; speedup vs baseline: 1.1837x; 1.1837x over previous
//
#include <hip/hip_runtime.h>
#include <hip/hip_bf16.h>

// DiscoMixerBlock: B=1, H=90, W=180 (P=16200), MODEL_DIM=130 (L=128),
// NH=8, HD=16, S=16, K=25, NNB=25, MH=32, FH=256. All fp32.
#define P_TOT 16200
#define MODEL_DIMC 130
#define L_DIM 128
#define NHH 8
#define S_DIM 16
#define K_DIM 25
#define NNBC 25
#define MH_DIM 32
#define FH_DIM 256

// exact gelu: x * 0.5 * (1 + erf(x/sqrt(2))); erf via Abramowitz-Stegun 7.1.26 (|err|<=1.5e-7)
__device__ __forceinline__ float gelu_f(float x) {
    float z = fabsf(x) * 0.70710678118654752440f;
    float t = __builtin_amdgcn_rcpf(fmaf(0.3275911f, z, 1.0f));
    float poly = t * fmaf(t, fmaf(t, fmaf(t, fmaf(t, 1.061405429f, -1.453152027f),
                                          1.421413741f), -0.284496736f), 0.254829592f);
    float e = __expf(-z * z);
    float erfp = fmaf(-poly, e, 1.0f);     // erf(|x|/sqrt2), >=0
    float erfv = copysignf(erfp, x);
    return 0.5f * x * (1.0f + erfv);
}

// ---------------- K0: transpose head_w1 [h][s][m] -> w1t [h][m][s] (4096 elems) ----------------
__global__ __launch_bounds__(256) void k0_transpose_w1(const float* __restrict__ hw1,
                                                       float* __restrict__ w1t) {
    int i = blockIdx.x * 256 + threadIdx.x;
    if (i < NHH * S_DIM * MH_DIM) {
        int h = i >> 9, s = (i >> 5) & 15, m = i & 31;
        w1t[h * 512 + m * 16 + s] = hw1[i];
    }
}

// ---------------- K1: bw[p][n][s] = sum_k disco_w[s][k] * basis[k][p][n] ----------------
__global__ __launch_bounds__(256) void k1_bw(const float* __restrict__ basis,
                                             const float* __restrict__ disco_w,
                                             float* __restrict__ bw) {
    __shared__ float w[S_DIM * K_DIM];   // [s][k]
    int tid = threadIdx.x;
    for (int i = tid; i < S_DIM * K_DIM; i += 256) w[i] = disco_w[i];
    __syncthreads();
    int i = blockIdx.x * 256 + tid;      // flat (p,n)
    if (i >= P_TOT * NNBC) return;
    float bv[K_DIM];
#pragma unroll
    for (int k = 0; k < K_DIM; k++) bv[k] = basis[k * (P_TOT * NNBC) + i];
    float acc[S_DIM];
#pragma unroll
    for (int s = 0; s < S_DIM; s++) {
        float a = 0.f;
#pragma unroll
        for (int k = 0; k < K_DIM; k++) a = fmaf(w[s * K_DIM + k], bv[k], a);
        acc[s] = a;
    }
    float4* outp = (float4*)(bw + (size_t)i * S_DIM);
#pragma unroll
    for (int q = 0; q < 4; q++) {
        float4 v; v.x = acc[q*4+0]; v.y = acc[q*4+1]; v.z = acc[q*4+2]; v.w = acc[q*4+3];
        outp[q] = v;
    }
}

// ---------------- K2: fused disco gather-dot + head MLP + residual -> xmix[p][c] ----------------
// Block = 4 waves = 4 points. Phase 1: wave = point, lane owns channels {lane, lane+64};
// all 25 nbr idx preloaded to SGPRs; bw in small 2-neighbor scalar chunks (34 live SGPRs).
// Phase 3: wave = head (x2 sequential), lanes = 4 pts x 16 d; w1t rows via s_load.
#define YSTR 2056   // per-point LDS stride: (ptl*2056) % 32 = ptl*8 -> conflict-free reads
__global__ __launch_bounds__(256, 2) void k2_disco_head(
        const float* __restrict__ x, const int* __restrict__ nbr,
        const float* __restrict__ bw, const float* __restrict__ w1t,
        const float* __restrict__ head_b1, const float* __restrict__ head_w2,
        const float* __restrict__ head_b2, const float* __restrict__ disco_b,
        float* __restrict__ xmix) {
    __shared__ float ylds[4 * YSTR];     // [pt][s][c]: pt*YSTR + s*128 + c

    int tid  = threadIdx.x;
    int lane = tid & 63;
    int wv   = __builtin_amdgcn_readfirstlane(tid >> 6);   // uniform wave id 0..3
    int p0   = blockIdx.x * 4;
    int p    = p0 + wv;                                    // uniform point

    const float* bwp = bw + (size_t)p * (NNBC * S_DIM);    // uniform base
    const int*   nbp = nbr + p * NNBC;                     // uniform base

    // preload all 25 neighbor indices (uniform -> ~25 SGPRs, 3 SMEM loads)
    int un[NNBC];
#pragma unroll
    for (int j = 0; j < NNBC; j++) un[j] = nbp[j];

    float y0[16], y1[16];
#pragma unroll
    for (int s = 0; s < 16; s++) { float db = disco_b[s]; y0[s] = db; y1[s] = db; }

    const float* xb0 = x + lane;
    const float* xb1 = x + 64 + lane;

    // 12 chunks of 2 neighbors (32 bw floats live in SGPRs per chunk), then tail n=24
#pragma unroll 1
    for (int nb = 0; nb < 24; nb += 2) {
        int u0 = un[nb], u1 = un[nb + 1];
        float g00 = xb0[(size_t)u0 * MODEL_DIMC];
        float g01 = xb1[(size_t)u0 * MODEL_DIMC];
        float g10 = xb0[(size_t)u1 * MODEL_DIMC];
        float g11 = xb1[(size_t)u1 * MODEL_DIMC];
#pragma unroll
        for (int s = 0; s < 16; s++) {
            float w0 = bwp[nb * 16 + s];           // uniform -> SGPR
            float w1_ = bwp[nb * 16 + 16 + s];     // uniform -> SGPR
            y0[s] = fmaf(g00, w0, y0[s]);
            y1[s] = fmaf(g01, w0, y1[s]);
            y0[s] = fmaf(g10, w1_, y0[s]);
            y1[s] = fmaf(g11, w1_, y1[s]);
        }
    }
    {
        int u = un[24];
        float g0 = xb0[(size_t)u * MODEL_DIMC];
        float g1 = xb1[(size_t)u * MODEL_DIMC];
#pragma unroll
        for (int s = 0; s < 16; s++) {
            float wv_ = bwp[24 * 16 + s];
            y0[s] = fmaf(g0, wv_, y0[s]);
            y1[s] = fmaf(g1, wv_, y1[s]);
        }
    }

    // Phase 2: y -> LDS (consecutive lanes -> conflict-free)
#pragma unroll
    for (int s = 0; s < 16; s++) {
        ylds[wv * YSTR + s * 128 + lane]      = y0[s];
        ylds[wv * YSTR + s * 128 + 64 + lane] = y1[s];
    }
    __syncthreads();

    // Phase 3: wave handles heads {wv, wv+4}; lane -> (ptl = lane>>4, d = lane&15)
    int ptl = lane >> 4;
    int d   = lane & 15;
#pragma unroll
    for (int t = 0; t < 2; t++) {
        int hh = __builtin_amdgcn_readfirstlane(wv + 4 * t);
        float yv[16];
#pragma unroll
        for (int s = 0; s < 16; s++)
            yv[s] = ylds[ptl * YSTR + s * 128 + hh * 16 + d];   // banks 8*ptl+d: unique
        const float* wrow = w1t + hh * (MH_DIM * S_DIM);        // uniform
        const float* b1r  = head_b1 + hh * MH_DIM;
        const float* w2r  = head_w2 + hh * MH_DIM;
        float acc = head_b2[hh];
#pragma unroll 2
        for (int m = 0; m < MH_DIM; m++) {
            float a = b1r[m];                                   // uniform -> SGPR
#pragma unroll
            for (int s = 0; s < 16; s++)
                a = fmaf(yv[s], wrow[m * 16 + s], a);           // w uniform -> SGPR
            a = gelu_f(a);
            acc = fmaf(a, w2r[m], acc);
        }
        int pp = p0 + ptl;
        int c  = hh * 16 + d;
        xmix[pp * L_DIM + c] = acc + x[(size_t)pp * MODEL_DIMC + c];
    }
}

// ---------------- K3a: hf[p][f] = gelu(xmix[p][:128] @ w1[:128][f] + b1[f]) ----------------
// TILE_P=16; 256 threads = 64 fid (4 f each: whole w1 row per wave, zero redundancy)
//                        x  4 pid (4 pts each)
__global__ __launch_bounds__(256, 2) void k3a_ffn1(
        const float* __restrict__ xmix, const float* __restrict__ w1,
        const float* __restrict__ b1, float* __restrict__ hf) {
    __shared__ __align__(16) float xm[16 * 132];    // padded stride 132
    int tid = threadIdx.x;
    int p0 = blockIdx.x * 16;
    int valid = min(16, P_TOT - p0);
    {
        const float4* src = (const float4*)(xmix + (size_t)p0 * L_DIM);
        for (int j = tid; j < valid * 32; j += 256) {
            float4 v = src[j];
            int pt = j >> 5, q = j & 31;
            *(float4*)&xm[pt * 132 + q * 4] = v;
        }
    }
    __syncthreads();

    int fid = tid & 63, pid = tid >> 6;
    int f0 = fid * 4;
    float4 bb = *(const float4*)&b1[f0];
    float acc[4][4];                                 // [pt][f]
#pragma unroll
    for (int i = 0; i < 4; i++) {
        acc[i][0] = bb.x; acc[i][1] = bb.y; acc[i][2] = bb.z; acc[i][3] = bb.w;
    }
#pragma unroll 2
    for (int k0 = 0; k0 < 128; k0 += 4) {
        float4 w4[4];
#pragma unroll
        for (int j = 0; j < 4; j++)
            w4[j] = *(const float4*)&w1[(k0 + j) * FH_DIM + f0];
#pragma unroll
        for (int i = 0; i < 4; i++) {
            float4 xv = *(const float4*)&xm[(pid * 4 + i) * 132 + k0];  // LDS broadcast
            acc[i][0] = fmaf(xv.x, w4[0].x, acc[i][0]);
            acc[i][1] = fmaf(xv.x, w4[0].y, acc[i][1]);
            acc[i][2] = fmaf(xv.x, w4[0].z, acc[i][2]);
            acc[i][3] = fmaf(xv.x, w4[0].w, acc[i][3]);
            acc[i][0] = fmaf(xv.y, w4[1].x, acc[i][0]);
            acc[i][1] = fmaf(xv.y, w4[1].y, acc[i][1]);
            acc[i][2] = fmaf(xv.y, w4[1].z, acc[i][2]);
            acc[i][3] = fmaf(xv.y, w4[1].w, acc[i][3]);
            acc[i][0] = fmaf(xv.z, w4[2].x, acc[i][0]);
            acc[i][1] = fmaf(xv.z, w4[2].y, acc[i][1]);
            acc[i][2] = fmaf(xv.z, w4[2].z, acc[i][2]);
            acc[i][3] = fmaf(xv.z, w4[2].w, acc[i][3]);
            acc[i][0] = fmaf(xv.w, w4[3].x, acc[i][0]);
            acc[i][1] = fmaf(xv.w, w4[3].y, acc[i][1]);
            acc[i][2] = fmaf(xv.w, w4[3].z, acc[i][2]);
            acc[i][3] = fmaf(xv.w, w4[3].w, acc[i][3]);
        }
    }
#pragma unroll
    for (int i = 0; i < 4; i++) {
        int pl = pid * 4 + i;
        if (pl < valid) {
            float4 v;
            v.x = gelu_f(acc[i][0]);
            v.y = gelu_f(acc[i][1]);
            v.z = gelu_f(acc[i][2]);
            v.w = gelu_f(acc[i][3]);
            *(float4*)&hf[(size_t)(p0 + pl) * FH_DIM + f0] = v;
        }
    }
}

// ---------------- K3b: out[p][l] = hf[p][:] @ w2[:][l] + b2[l] + xmix[p][l]; +sincos ----------------
// TILE_P=16; 256 threads = 32 lid (4 l each: half w2 row per 32-lane group) x 8 pid (2 pts each)
__global__ __launch_bounds__(256, 2) void k3b_ffn2(
        const float* __restrict__ x, const float* __restrict__ xmix,
        const float* __restrict__ hf, const float* __restrict__ w2,
        const float* __restrict__ b2, float* __restrict__ out) {
    __shared__ __align__(16) float hfl[16 * 264];   // padded stride 264
    int tid = threadIdx.x;
    int p0 = blockIdx.x * 16;
    int valid = min(16, P_TOT - p0);
    {
        const float4* src = (const float4*)(hf + (size_t)p0 * FH_DIM);
        for (int j = tid; j < valid * 64; j += 256) {
            float4 v = src[j];
            int pt = j >> 6, q = j & 63;
            *(float4*)&hfl[pt * 264 + q * 4] = v;
        }
    }
    __syncthreads();

    int lid = tid & 31, pid = tid >> 5;
    int l0 = lid * 4;
    float4 bb = *(const float4*)&b2[l0];
    float acc[2][4];                                 // [pt][l]
#pragma unroll
    for (int i = 0; i < 2; i++) {
        acc[i][0] = bb.x; acc[i][1] = bb.y; acc[i][2] = bb.z; acc[i][3] = bb.w;
    }
#pragma unroll 2
    for (int f0 = 0; f0 < FH_DIM; f0 += 4) {
        float4 w4[4];
#pragma unroll
        for (int j = 0; j < 4; j++)
            w4[j] = *(const float4*)&w2[(f0 + j) * L_DIM + l0];
#pragma unroll
        for (int i = 0; i < 2; i++) {
            float4 hv = *(const float4*)&hfl[(pid * 2 + i) * 264 + f0];  // LDS broadcast
            acc[i][0] = fmaf(hv.x, w4[0].x, acc[i][0]);
            acc[i][1] = fmaf(hv.x, w4[0].y, acc[i][1]);
            acc[i][2] = fmaf(hv.x, w4[0].z, acc[i][2]);
            acc[i][3] = fmaf(hv.x, w4[0].w, acc[i][3]);
            acc[i][0] = fmaf(hv.y, w4[1].x, acc[i][0]);
            acc[i][1] = fmaf(hv.y, w4[1].y, acc[i][1]);
            acc[i][2] = fmaf(hv.y, w4[1].z, acc[i][2]);
            acc[i][3] = fmaf(hv.y, w4[1].w, acc[i][3]);
            acc[i][0] = fmaf(hv.z, w4[2].x, acc[i][0]);
            acc[i][1] = fmaf(hv.z, w4[2].y, acc[i][1]);
            acc[i][2] = fmaf(hv.z, w4[2].z, acc[i][2]);
            acc[i][3] = fmaf(hv.z, w4[2].w, acc[i][3]);
            acc[i][0] = fmaf(hv.w, w4[3].x, acc[i][0]);
            acc[i][1] = fmaf(hv.w, w4[3].y, acc[i][1]);
            acc[i][2] = fmaf(hv.w, w4[3].z, acc[i][2]);
            acc[i][3] = fmaf(hv.w, w4[3].w, acc[i][3]);
        }
    }
#pragma unroll
    for (int i = 0; i < 2; i++) {
        int pl = pid * 2 + i;
        if (pl < valid) {
            int pp = p0 + pl;
            float4 xm4 = *(const float4*)&xmix[(size_t)pp * L_DIM + l0];
            float2 o01, o23;
            o01.x = acc[i][0] + xm4.x;
            o01.y = acc[i][1] + xm4.y;
            o23.x = acc[i][2] + xm4.z;
            o23.y = acc[i][3] + xm4.w;
            *(float2*)&out[(size_t)pp * MODEL_DIMC + l0]     = o01;
            *(float2*)&out[(size_t)pp * MODEL_DIMC + l0 + 2] = o23;
        }
    }
    if (tid < 32) {
        int pt = tid >> 1, wch = tid & 1;
        if (pt < valid) {
            int pp = p0 + pt;
            out[(size_t)pp * MODEL_DIMC + 128 + wch] = x[(size_t)pp * MODEL_DIMC + 128 + wch];
        }
    }
}

extern "C" void kernel_launch(void* const* d_in, const int* in_sizes, int n_in,
                              void* d_out, int out_size, void* d_ws, size_t ws_size,
                              hipStream_t stream) {
    const float* x        = (const float*)d_in[0];
    const int*   nbr      = (const int*)  d_in[1];
    const float* basis    = (const float*)d_in[2];
    const float* disco_w  = (const float*)d_in[3];
    const float* disco_b  = (const float*)d_in[4];
    const float* head_w1  = (const float*)d_in[5];
    const float* head_b1  = (const float*)d_in[6];
    const float* head_w2  = (const float*)d_in[7];
    const float* head_b2  = (const float*)d_in[8];
    const float* ffn_w1   = (const float*)d_in[9];
    const float* ffn_b1   = (const float*)d_in[10];
    const float* ffn_w2   = (const float*)d_in[11];
    const float* ffn_b2   = (const float*)d_in[12];
    float* out = (float*)d_out;

    // ws layout: bw [P*400] (25.9MB) | xmix [P*128] (8.3MB) | w1t [4096] (16KB)
    // hf [P*256] aliases bw (bw dead after k2).
    float* bw   = (float*)d_ws;
    float* xmix = bw + (size_t)P_TOT * NNBC * S_DIM;
    float* w1t  = xmix + (size_t)P_TOT * L_DIM;
    float* hf   = bw;

    hipLaunchKernelGGL(k0_transpose_w1, dim3(16), dim3(256), 0, stream, head_w1, w1t);
    hipLaunchKernelGGL(k1_bw, dim3((P_TOT * NNBC + 255) / 256), dim3(256), 0, stream,
                       basis, disco_w, bw);
    hipLaunchKernelGGL(k2_disco_head, dim3(P_TOT / 4), dim3(256), 0, stream,
                       x, nbr, bw, w1t, head_b1, head_w2, head_b2, disco_b, xmix);
    hipLaunchKernelGGL(k3a_ffn1, dim3((P_TOT + 15) / 16), dim3(256), 0, stream,
                       xmix, ffn_w1, ffn_b1, hf);
    hipLaunchKernelGGL(k3b_ffn2, dim3((P_TOT + 15) / 16), dim3(256), 0, stream,
                       x, xmix, hf, ffn_w2, ffn_b2, out);
}

// Round 5
// 269.833 us; speedup vs baseline: 1.1969x; 1.0111x over previous
//
#include <hip/hip_runtime.h>
#include <hip/hip_bf16.h>

// DiscoMixerBlock: B=1, H=90, W=180 (P=16200), MODEL_DIM=130 (L=128),
// NH=8, HD=16, S=16, K=25, NNB=25, MH=32, FH=256. All fp32.
#define P_TOT 16200
#define MODEL_DIMC 130
#define L_DIM 128
#define NHH 8
#define S_DIM 16
#define K_DIM 25
#define NNBC 25
#define MH_DIM 32
#define FH_DIM 256

// exact gelu: x * 0.5 * (1 + erf(x/sqrt(2))); erf via Abramowitz-Stegun 7.1.26 (|err|<=1.5e-7)
__device__ __forceinline__ float gelu_f(float x) {
    float z = fabsf(x) * 0.70710678118654752440f;
    float t = __builtin_amdgcn_rcpf(fmaf(0.3275911f, z, 1.0f));
    float poly = t * fmaf(t, fmaf(t, fmaf(t, fmaf(t, 1.061405429f, -1.453152027f),
                                          1.421413741f), -0.284496736f), 0.254829592f);
    float e = __expf(-z * z);
    float erfp = fmaf(-poly, e, 1.0f);     // erf(|x|/sqrt2), >=0
    float erfv = copysignf(erfp, x);
    return 0.5f * x * (1.0f + erfv);
}

// ---------------- K1: bw[p][n][s] = sum_k disco_w[s][k] * basis[k][p][n] ----------------
// tail blocks (>= NB1) transpose head_w1 [h][s][m] -> w1t [h][m][s]
#define NB1 1583   // ceil(405000/256)
__global__ __launch_bounds__(256) void k1_bw_t(const float* __restrict__ basis,
                                               const float* __restrict__ disco_w,
                                               const float* __restrict__ hw1,
                                               float* __restrict__ bw,
                                               float* __restrict__ w1t) {
    int bid = blockIdx.x;
    int tid = threadIdx.x;
    if (bid >= NB1) {                    // block-uniform branch (no divergent barrier)
        int i = (bid - NB1) * 256 + tid;
        if (i < NHH * S_DIM * MH_DIM) {
            int h = i >> 9, s = (i >> 5) & 15, m = i & 31;
            w1t[h * 512 + m * 16 + s] = hw1[i];
        }
        return;
    }
    __shared__ float w[S_DIM * K_DIM];   // [s][k]
    for (int i = tid; i < S_DIM * K_DIM; i += 256) w[i] = disco_w[i];
    __syncthreads();
    int i = bid * 256 + tid;             // flat (p,n)
    if (i >= P_TOT * NNBC) return;
    float bv[K_DIM];
#pragma unroll
    for (int k = 0; k < K_DIM; k++) bv[k] = basis[k * (P_TOT * NNBC) + i];
    float acc[S_DIM];
#pragma unroll
    for (int s = 0; s < S_DIM; s++) {
        float a = 0.f;
#pragma unroll
        for (int k = 0; k < K_DIM; k++) a = fmaf(w[s * K_DIM + k], bv[k], a);
        acc[s] = a;
    }
    float4* outp = (float4*)(bw + (size_t)i * S_DIM);
#pragma unroll
    for (int q = 0; q < 4; q++) {
        float4 v; v.x = acc[q*4+0]; v.y = acc[q*4+1]; v.z = acc[q*4+2]; v.w = acc[q*4+3];
        outp[q] = v;
    }
}

// ---------------- K2: fused disco gather-dot + head MLP + residual -> xmix[p][c] ----------------
// Block = 4 waves = 4 points. Phase 1: wave = point, lane owns channels {lane, lane+64};
// nbr/bw via wave-uniform s_load (2-neighbor chunks, ~36 live SGPRs).
// LDS y-tile: 4*2048 floats = 32768 B exactly -> 5 blocks/CU. Rotation swizzle
// col=(c+8*pt)&127 keeps BOTH write (consecutive) and read (d+8*ptl+16*hh) at 2 lanes/bank (free).
__global__ __launch_bounds__(256, 5) void k2_disco_head(
        const float* __restrict__ x, const int* __restrict__ nbr,
        const float* __restrict__ bw, const float* __restrict__ w1t,
        const float* __restrict__ head_b1, const float* __restrict__ head_w2,
        const float* __restrict__ head_b2, const float* __restrict__ disco_b,
        float* __restrict__ xmix) {
    __shared__ float ylds[4 * 2048];     // [pt][s][colrot]

    int tid  = threadIdx.x;
    int lane = tid & 63;
    int wv   = __builtin_amdgcn_readfirstlane(tid >> 6);   // uniform wave id 0..3
    int p0   = blockIdx.x * 4;
    int p    = p0 + wv;                                    // uniform point

    const float* bwp = bw + (size_t)p * (NNBC * S_DIM);    // uniform base (64B-aligned rows)
    const int*   nbp = nbr + p * NNBC;                     // uniform base

    float y0[16], y1[16];
#pragma unroll
    for (int s = 0; s < 16; s++) { float db = disco_b[s]; y0[s] = db; y1[s] = db; }

    const float* xb0 = x + lane;
    const float* xb1 = x + 64 + lane;

    // 12 chunks of 2 neighbors (32 bw floats live in SGPRs per chunk), then tail n=24
#pragma unroll 1
    for (int nb = 0; nb < 24; nb += 2) {
        int u0 = nbp[nb], u1 = nbp[nb + 1];                // uniform -> SGPR
        float g00 = xb0[(size_t)u0 * MODEL_DIMC];
        float g01 = xb1[(size_t)u0 * MODEL_DIMC];
        float g10 = xb0[(size_t)u1 * MODEL_DIMC];
        float g11 = xb1[(size_t)u1 * MODEL_DIMC];
#pragma unroll
        for (int s = 0; s < 16; s++) {
            float w0  = bwp[nb * 16 + s];                  // uniform -> SGPR
            float w1_ = bwp[nb * 16 + 16 + s];             // uniform -> SGPR
            y0[s] = fmaf(g00, w0, y0[s]);
            y1[s] = fmaf(g01, w0, y1[s]);
            y0[s] = fmaf(g10, w1_, y0[s]);
            y1[s] = fmaf(g11, w1_, y1[s]);
        }
    }
    {
        int u = nbp[24];
        float g0 = xb0[(size_t)u * MODEL_DIMC];
        float g1 = xb1[(size_t)u * MODEL_DIMC];
#pragma unroll
        for (int s = 0; s < 16; s++) {
            float wv_ = bwp[24 * 16 + s];
            y0[s] = fmaf(g0, wv_, y0[s]);
            y1[s] = fmaf(g1, wv_, y1[s]);
        }
    }

    // Phase 2: y -> LDS, rotated columns (consecutive mod 128 -> 2 lanes/bank = free)
    int cr0 = (lane + 8 * wv) & 127;
    int cr1 = (cr0 + 64) & 127;
#pragma unroll
    for (int s = 0; s < 16; s++) {
        ylds[wv * 2048 + s * 128 + cr0] = y0[s];
        ylds[wv * 2048 + s * 128 + cr1] = y1[s];
    }
    __syncthreads();

    // Phase 3: wave handles heads {wv, wv+4}; lane -> (ptl = lane>>4, d = lane&15)
    int ptl = lane >> 4;
    int d   = lane & 15;
    int ybase = ptl * 2048;
    int rot   = 8 * ptl;
#pragma unroll
    for (int t = 0; t < 2; t++) {
        int hh = __builtin_amdgcn_readfirstlane(wv + 4 * t);
        int cc  = hh * 16 + d;
        int col = (cc + rot) & 127;
        float yv[16];
#pragma unroll
        for (int s = 0; s < 16; s++)
            yv[s] = ylds[ybase + s * 128 + col];           // 2 lanes/bank: free
        const float* wrow = w1t + hh * (MH_DIM * S_DIM);   // uniform
        const float* b1r  = head_b1 + hh * MH_DIM;
        const float* w2r  = head_w2 + hh * MH_DIM;
        float acc = head_b2[hh];
        // 2 m's in flight, each dot split into 2 partials: 4 independent 8-FMA chains
#pragma unroll 1
        for (int m = 0; m < MH_DIM; m += 2) {
            const float* wm0 = wrow + m * 16;
            const float* wm1 = wrow + m * 16 + 16;
            float a0 = b1r[m], a1 = b1r[m + 1];
            float a0b = 0.f, a1b = 0.f;
#pragma unroll
            for (int s = 0; s < 8; s++) {
                a0  = fmaf(yv[s],     wm0[s],     a0);
                a0b = fmaf(yv[s + 8], wm0[s + 8], a0b);
                a1  = fmaf(yv[s],     wm1[s],     a1);
                a1b = fmaf(yv[s + 8], wm1[s + 8], a1b);
            }
            a0 += a0b; a1 += a1b;
            a0 = gelu_f(a0);                               // two independent gelu chains
            a1 = gelu_f(a1);
            acc = fmaf(a0, w2r[m],     acc);
            acc = fmaf(a1, w2r[m + 1], acc);
        }
        int pp = p0 + ptl;
        xmix[pp * L_DIM + cc] = acc + x[(size_t)pp * MODEL_DIMC + cc];
    }
}

// ---------------- K3: fused FFN. 16 pts/block; hf kept in LDS (no HBM round-trip) ----------------
// Phase A: fid=tid&63 -> 4 f (full w1 row per wave, zero redundancy), wid=tid>>6 -> 4 pts.
// Phase B: lid=tid&31 -> 4 l, pgb=tid>>5 -> 2 pts.
__global__ __launch_bounds__(256) void k3_ffn(
        const float* __restrict__ x, const float* __restrict__ xmix,
        const float* __restrict__ w1, const float* __restrict__ b1,
        const float* __restrict__ w2, const float* __restrict__ b2,
        float* __restrict__ out) {
    __shared__ __align__(16) float xm[16 * 132];    // 8.4 KB, padded stride 132
    __shared__ __align__(16) float hfl[16 * 260];   // 16.6 KB, padded stride 260
    int tid = threadIdx.x;
    int p0 = blockIdx.x * 16;
    int valid = min(16, P_TOT - p0);
    {
        const float4* src = (const float4*)(xmix + (size_t)p0 * L_DIM);
        for (int j = tid; j < valid * 32; j += 256) {
            float4 v = src[j];
            int pt = j >> 5, q = j & 31;
            *(float4*)&xm[pt * 132 + q * 4] = v;
        }
    }
    __syncthreads();

    // Phase A: hf = gelu(xm @ w1 + b1)
    {
        int fid = tid & 63, wid = tid >> 6;
        int f0 = fid * 4;
        float4 bb = *(const float4*)&b1[f0];
        float acc[4][4];                             // [pt][f]
#pragma unroll
        for (int i = 0; i < 4; i++) {
            acc[i][0] = bb.x; acc[i][1] = bb.y; acc[i][2] = bb.z; acc[i][3] = bb.w;
        }
#pragma unroll 2
        for (int k0 = 0; k0 < 128; k0 += 4) {
            float4 w4[4];
#pragma unroll
            for (int j = 0; j < 4; j++)
                w4[j] = *(const float4*)&w1[(k0 + j) * FH_DIM + f0];
#pragma unroll
            for (int i = 0; i < 4; i++) {
                float4 xv = *(const float4*)&xm[(wid * 4 + i) * 132 + k0];  // LDS broadcast
                acc[i][0] = fmaf(xv.x, w4[0].x, acc[i][0]);
                acc[i][1] = fmaf(xv.x, w4[0].y, acc[i][1]);
                acc[i][2] = fmaf(xv.x, w4[0].z, acc[i][2]);
                acc[i][3] = fmaf(xv.x, w4[0].w, acc[i][3]);
                acc[i][0] = fmaf(xv.y, w4[1].x, acc[i][0]);
                acc[i][1] = fmaf(xv.y, w4[1].y, acc[i][1]);
                acc[i][2] = fmaf(xv.y, w4[1].z, acc[i][2]);
                acc[i][3] = fmaf(xv.y, w4[1].w, acc[i][3]);
                acc[i][0] = fmaf(xv.z, w4[2].x, acc[i][0]);
                acc[i][1] = fmaf(xv.z, w4[2].y, acc[i][1]);
                acc[i][2] = fmaf(xv.z, w4[2].z, acc[i][2]);
                acc[i][3] = fmaf(xv.z, w4[2].w, acc[i][3]);
                acc[i][0] = fmaf(xv.w, w4[3].x, acc[i][0]);
                acc[i][1] = fmaf(xv.w, w4[3].y, acc[i][1]);
                acc[i][2] = fmaf(xv.w, w4[3].z, acc[i][2]);
                acc[i][3] = fmaf(xv.w, w4[3].w, acc[i][3]);
            }
        }
#pragma unroll
        for (int i = 0; i < 4; i++) {
            int pt = wid * 4 + i;
            float4 v;
            v.x = gelu_f(acc[i][0]);
            v.y = gelu_f(acc[i][1]);
            v.z = gelu_f(acc[i][2]);
            v.w = gelu_f(acc[i][3]);
            *(float4*)&hfl[pt * 260 + f0] = v;
        }
    }
    __syncthreads();

    // Phase B: out = hfl @ w2 + b2 + xm (+ sincos passthrough)
    {
        int lid = tid & 31, pgb = tid >> 5;
        int l0 = lid * 4;
        float4 bb = *(const float4*)&b2[l0];
        float acc[2][4];                             // [pt][l]
#pragma unroll
        for (int i = 0; i < 2; i++) {
            acc[i][0] = bb.x; acc[i][1] = bb.y; acc[i][2] = bb.z; acc[i][3] = bb.w;
        }
#pragma unroll 2
        for (int f0 = 0; f0 < FH_DIM; f0 += 4) {
            float4 w4[4];
#pragma unroll
            for (int j = 0; j < 4; j++)
                w4[j] = *(const float4*)&w2[(f0 + j) * L_DIM + l0];
#pragma unroll
            for (int i = 0; i < 2; i++) {
                float4 hv = *(const float4*)&hfl[(pgb * 2 + i) * 260 + f0];  // LDS broadcast
                acc[i][0] = fmaf(hv.x, w4[0].x, acc[i][0]);
                acc[i][1] = fmaf(hv.x, w4[0].y, acc[i][1]);
                acc[i][2] = fmaf(hv.x, w4[0].z, acc[i][2]);
                acc[i][3] = fmaf(hv.x, w4[0].w, acc[i][3]);
                acc[i][0] = fmaf(hv.y, w4[1].x, acc[i][0]);
                acc[i][1] = fmaf(hv.y, w4[1].y, acc[i][1]);
                acc[i][2] = fmaf(hv.y, w4[1].z, acc[i][2]);
                acc[i][3] = fmaf(hv.y, w4[1].w, acc[i][3]);
                acc[i][0] = fmaf(hv.z, w4[2].x, acc[i][0]);
                acc[i][1] = fmaf(hv.z, w4[2].y, acc[i][1]);
                acc[i][2] = fmaf(hv.z, w4[2].z, acc[i][2]);
                acc[i][3] = fmaf(hv.z, w4[2].w, acc[i][3]);
                acc[i][0] = fmaf(hv.w, w4[3].x, acc[i][0]);
                acc[i][1] = fmaf(hv.w, w4[3].y, acc[i][1]);
                acc[i][2] = fmaf(hv.w, w4[3].z, acc[i][2]);
                acc[i][3] = fmaf(hv.w, w4[3].w, acc[i][3]);
            }
        }
#pragma unroll
        for (int i = 0; i < 2; i++) {
            int pl = pgb * 2 + i;
            if (pl < valid) {
                int pp = p0 + pl;
                float4 xm4 = *(const float4*)&xm[pl * 132 + l0];
                float2 o01, o23;
                o01.x = acc[i][0] + xm4.x;
                o01.y = acc[i][1] + xm4.y;
                o23.x = acc[i][2] + xm4.z;
                o23.y = acc[i][3] + xm4.w;
                *(float2*)&out[(size_t)pp * MODEL_DIMC + l0]     = o01;
                *(float2*)&out[(size_t)pp * MODEL_DIMC + l0 + 2] = o23;
            }
        }
        if (tid < 32) {
            int pt = tid >> 1, wch = tid & 1;
            if (pt < valid) {
                int pp = p0 + pt;
                out[(size_t)pp * MODEL_DIMC + 128 + wch] = x[(size_t)pp * MODEL_DIMC + 128 + wch];
            }
        }
    }
}

extern "C" void kernel_launch(void* const* d_in, const int* in_sizes, int n_in,
                              void* d_out, int out_size, void* d_ws, size_t ws_size,
                              hipStream_t stream) {
    const float* x        = (const float*)d_in[0];
    const int*   nbr      = (const int*)  d_in[1];
    const float* basis    = (const float*)d_in[2];
    const float* disco_w  = (const float*)d_in[3];
    const float* disco_b  = (const float*)d_in[4];
    const float* head_w1  = (const float*)d_in[5];
    const float* head_b1  = (const float*)d_in[6];
    const float* head_w2  = (const float*)d_in[7];
    const float* head_b2  = (const float*)d_in[8];
    const float* ffn_w1   = (const float*)d_in[9];
    const float* ffn_b1   = (const float*)d_in[10];
    const float* ffn_w2   = (const float*)d_in[11];
    const float* ffn_b2   = (const float*)d_in[12];
    float* out = (float*)d_out;

    // ws layout: bw [P*400] (25.9MB) | xmix [P*128] (8.3MB) | w1t [4096] (16KB)
    float* bw   = (float*)d_ws;
    float* xmix = bw + (size_t)P_TOT * NNBC * S_DIM;
    float* w1t  = xmix + (size_t)P_TOT * L_DIM;

    hipLaunchKernelGGL(k1_bw_t, dim3(NB1 + 16), dim3(256), 0, stream,
                       basis, disco_w, head_w1, bw, w1t);
    hipLaunchKernelGGL(k2_disco_head, dim3(P_TOT / 4), dim3(256), 0, stream,
                       x, nbr, bw, w1t, head_b1, head_w2, head_b2, disco_b, xmix);
    hipLaunchKernelGGL(k3_ffn, dim3((P_TOT + 15) / 16), dim3(256), 0, stream,
                       x, xmix, ffn_w1, ffn_b1, ffn_w2, ffn_b2, out);
}